// Round 1
// baseline (261.320 us; speedup 1.0000x reference)
//
#include <hip/hip_runtime.h>
#include <stdint.h>

typedef short short8 __attribute__((ext_vector_type(8)));
typedef __bf16 bf16x8 __attribute__((ext_vector_type(8)));
typedef float floatx4 __attribute__((ext_vector_type(4)));
typedef unsigned short u16;
typedef unsigned int u32;

#define NB 8
#define SL1 2048
#define SL2 2048
#define HD 512
#define QBLK 64
#define KVB 32
// log2(e)/sqrt(512)
#define SCL 0.063758717f

__device__ __forceinline__ u16 f2bf(float f) {
  u32 u = __float_as_uint(f);
  u = u + 0x7fffu + ((u >> 16) & 1u);   // RNE
  return (u16)(u >> 16);
}

// ---------------- prepass: K,V fp32 -> bf16 in workspace ----------------
__global__ void cvt_bf16_kernel(const float* __restrict__ K,
                                const float* __restrict__ V,
                                u16* __restrict__ Kb, u16* __restrict__ Vb) {
  const int n8 = NB * SL2 * HD / 8;  // 8-element chunks per tensor
  for (int c = blockIdx.x * blockDim.x + threadIdx.x; c < 2 * n8;
       c += gridDim.x * blockDim.x) {
    const float* src = (c < n8) ? K : V;
    u16* dst = (c < n8) ? Kb : Vb;
    size_t i = (size_t)(c < n8 ? c : c - n8) * 8;
    float4 f0 = *(const float4*)(src + i);
    float4 f1 = *(const float4*)(src + i + 4);
    short8 o;
    o[0] = (short)f2bf(f0.x); o[1] = (short)f2bf(f0.y);
    o[2] = (short)f2bf(f0.z); o[3] = (short)f2bf(f0.w);
    o[4] = (short)f2bf(f1.x); o[5] = (short)f2bf(f1.y);
    o[6] = (short)f2bf(f1.z); o[7] = (short)f2bf(f1.w);
    *(short8*)(dst + i) = o;
  }
}

// ---------------- flash attention ----------------
// grid = 256: blockIdx = qt*8 + b  (b == XCD via %8 round-robin)
// 8 waves: QK^T wave(wr=w>>1, wc=w&1) -> 16x16 S tile; PV wave w -> 64-col H slice
__global__ __launch_bounds__(512, 2)
void attn_fwd(const float* __restrict__ Qg, const u16* __restrict__ Kbf,
              const u16* __restrict__ Vbf, const void* __restrict__ lenp,
              float* __restrict__ Out) {
  __shared__ u16 Klds[KVB * HD];      // [kv][h], rows 1024B, XOR-swizzled
  __shared__ u16 Vscr[KVB * HD];      // [kv][h], row-major scratch
  __shared__ u16 Vt[HD * 40];         // [h][kv], pad to 40 (80B, 16B-aligned)
  __shared__ u16 Plds[QBLK * 40];     // [q][kv], pad to 40
  __shared__ float rowmax_sh[QBLK][2];
  __shared__ float rowsum_sh[QBLK][2];
  __shared__ float m_s[QBLK];
  __shared__ float l_s[QBLK];
  __shared__ float fac_s[QBLK];

  const int tid = threadIdx.x;
  const int lane = tid & 63;
  const int w = tid >> 6;
  const int wr = w >> 1, wc = w & 1;
  const int l15 = lane & 15, lg = lane >> 4;

  const int bx = blockIdx.x;
  const int b = bx & 7;
  const int q0 = (bx >> 3) * QBLK;

  // memory_length: detect int64 vs int32 at runtime (lengths[0]==2048 always)
  long long probe = ((const long long*)lenp)[0];
  int len;
  if (probe >= 1 && probe <= SL2) len = (int)((const long long*)lenp)[b];
  else len = ((const int*)lenp)[b];

  if (tid < QBLK) { m_s[tid] = -3.0e38f; l_s[tid] = 0.0f; }

  // Q fragments in registers: rows q0+wr*16+l15, A-frag k = ks*32 + lg*8 + j
  bf16x8 qf[16];
  {
    const float* qrow = Qg + ((size_t)b * SL1 + (q0 + wr * 16 + l15)) * HD;
    #pragma unroll
    for (int ks = 0; ks < 16; ++ks) {
      const float* p = qrow + ks * 32 + lg * 8;
      float4 f0 = *(const float4*)(p);
      float4 f1 = *(const float4*)(p + 4);
      short8 t;
      t[0] = (short)f2bf(f0.x); t[1] = (short)f2bf(f0.y);
      t[2] = (short)f2bf(f0.z); t[3] = (short)f2bf(f0.w);
      t[4] = (short)f2bf(f1.x); t[5] = (short)f2bf(f1.y);
      t[6] = (short)f2bf(f1.z); t[7] = (short)f2bf(f1.w);
      qf[ks] = __builtin_bit_cast(bf16x8, t);
    }
  }

  floatx4 of[4][4];  // O acc: [row-tile][col-tile], rows 64, cols w*64..+64
  #pragma unroll
  for (int i = 0; i < 4; ++i)
    #pragma unroll
    for (int j = 0; j < 4; ++j)
      of[i][j] = (floatx4){0.f, 0.f, 0.f, 0.f};

  __syncthreads();

  const size_t kvbase = (size_t)b * SL2 * HD;
  const int nit = (len + KVB - 1) / KVB;

  for (int it = 0; it < nit; ++it) {
    const int kv0 = it * KVB;

    // ---- stage K (swizzled) + V (scratch); wave covers one kv row ----
    #pragma unroll
    for (int i = 0; i < 4; ++i) {
      int id = i * 512 + tid;
      int r = id >> 6, c = id & 63;
      size_t goff = kvbase + (size_t)(kv0 + r) * HD + c * 8;
      short8 k8 = *(const short8*)(Kbf + goff);
      short8 v8 = *(const short8*)(Vbf + goff);
      *(short8*)((char*)Klds + r * 1024 + ((c * 16) ^ ((r & 7) << 4))) = k8;
      *(short8*)((char*)Vscr + r * 1024 + c * 16) = v8;
    }
    __syncthreads();

    // ---- transpose V into Vt[h=tid][kv] (conflict-free column reads) ----
    #pragma unroll
    for (int i = 0; i < 4; ++i) {
      short8 t8;
      #pragma unroll
      for (int j = 0; j < 8; ++j)
        t8[j] = (short)Vscr[(i * 8 + j) * HD + tid];
      *(short8*)((char*)Vt + tid * 80 + i * 16) = t8;
    }
    __syncthreads();

    // ---- QK^T: one 16x16 tile per wave, K=512 ----
    floatx4 s = (floatx4){0.f, 0.f, 0.f, 0.f};
    {
      const int krow = wc * 16 + l15;
      const char* kb = (const char*)Klds + krow * 1024;
      const int kxor = (krow & 7) << 4;
      #pragma unroll
      for (int ks = 0; ks < 16; ++ks) {
        bf16x8 kf = *(const bf16x8*)(kb + ((ks * 64 + lg * 16) ^ kxor));
        s = __builtin_amdgcn_mfma_f32_16x16x32_bf16(qf[ks], kf, s, 0, 0, 0);
      }
    }
    const int colg = kv0 + wc * 16 + l15;
    float sc[4];
    #pragma unroll
    for (int r = 0; r < 4; ++r) {
      float x = s[r] * SCL;
      sc[r] = (colg >= len) ? -3.0e38f : x;
    }
    // row max over the tile's 16 cols (cols live on l15 within 16-lane group)
    float rmx[4];
    #pragma unroll
    for (int r = 0; r < 4; ++r) {
      float m = sc[r];
      m = fmaxf(m, __shfl_xor(m, 1));
      m = fmaxf(m, __shfl_xor(m, 2));
      m = fmaxf(m, __shfl_xor(m, 4));
      m = fmaxf(m, __shfl_xor(m, 8));
      rmx[r] = m;
    }
    if (l15 == 0) {
      #pragma unroll
      for (int r = 0; r < 4; ++r) rowmax_sh[wr * 16 + lg * 4 + r][wc] = rmx[r];
    }
    __syncthreads();

    // ---- online softmax (exp2 domain) ----
    float mnew[4], fac[4], psm[4];
    #pragma unroll
    for (int r = 0; r < 4; ++r) {
      int row = wr * 16 + lg * 4 + r;
      float mo = m_s[row];
      float tm = fmaxf(rowmax_sh[row][0], rowmax_sh[row][1]);
      float mn = fmaxf(mo, tm);
      mnew[r] = mn;
      fac[r] = exp2f(mo - mn);
      float p = exp2f(sc[r] - mn);
      float sp = p;
      sp += __shfl_xor(sp, 1);
      sp += __shfl_xor(sp, 2);
      sp += __shfl_xor(sp, 4);
      sp += __shfl_xor(sp, 8);
      psm[r] = sp;
      Plds[row * 40 + wc * 16 + l15] = f2bf(p);
    }
    if (l15 == 0) {
      #pragma unroll
      for (int r = 0; r < 4; ++r) rowsum_sh[wr * 16 + lg * 4 + r][wc] = psm[r];
      if (wc == 0) {
        #pragma unroll
        for (int r = 0; r < 4; ++r) fac_s[wr * 16 + lg * 4 + r] = fac[r];
      }
    }
    __syncthreads();

    // ---- stats update (one lane set per row; reads both wave-col partials) ----
    if (wc == 0 && l15 == 0) {
      #pragma unroll
      for (int r = 0; r < 4; ++r) {
        int row = wr * 16 + lg * 4 + r;
        l_s[row] = l_s[row] * fac[r] + rowsum_sh[row][0] + rowsum_sh[row][1];
        m_s[row] = mnew[r];
      }
    }

    // ---- PV: rescale O, then O += P * V ----
    float fl[4][4];
    #pragma unroll
    for (int rt = 0; rt < 4; ++rt)
      #pragma unroll
      for (int r = 0; r < 4; ++r)
        fl[rt][r] = fac_s[rt * 16 + lg * 4 + r];
    #pragma unroll
    for (int rt = 0; rt < 4; ++rt)
      #pragma unroll
      for (int tc = 0; tc < 4; ++tc)
        #pragma unroll
        for (int r = 0; r < 4; ++r)
          of[rt][tc][r] *= fl[rt][r];

    bf16x8 pa[4], vbf[4];
    #pragma unroll
    for (int rt = 0; rt < 4; ++rt)
      pa[rt] = *(const bf16x8*)((const char*)Plds + (rt * 16 + l15) * 80 + lg * 16);
    #pragma unroll
    for (int tc = 0; tc < 4; ++tc)
      vbf[tc] = *(const bf16x8*)((const char*)Vt + (w * 64 + tc * 16 + l15) * 80 + lg * 16);
    #pragma unroll
    for (int rt = 0; rt < 4; ++rt)
      #pragma unroll
      for (int tc = 0; tc < 4; ++tc)
        of[rt][tc] = __builtin_amdgcn_mfma_f32_16x16x32_bf16(pa[rt], vbf[tc],
                                                             of[rt][tc], 0, 0, 0);
    __syncthreads();
  }

  // ---- epilogue: O / l ----
  float inv[4][4];
  #pragma unroll
  for (int rt = 0; rt < 4; ++rt)
    #pragma unroll
    for (int r = 0; r < 4; ++r)
      inv[rt][r] = 1.0f / l_s[rt * 16 + lg * 4 + r];
  #pragma unroll
  for (int rt = 0; rt < 4; ++rt) {
    #pragma unroll
    for (int r = 0; r < 4; ++r) {
      size_t row = (size_t)b * SL1 + q0 + rt * 16 + lg * 4 + r;
      float* orow = Out + row * HD + w * 64 + l15;
      #pragma unroll
      for (int tc = 0; tc < 4; ++tc)
        orow[tc * 16] = of[rt][tc][r] * inv[rt][r];
    }
  }
}

extern "C" void kernel_launch(void* const* d_in, const int* in_sizes, int n_in,
                              void* d_out, int out_size, void* d_ws, size_t ws_size,
                              hipStream_t stream) {
  const float* Q = (const float*)d_in[0];
  const float* K = (const float*)d_in[1];
  const float* V = (const float*)d_in[2];
  const void* lenp = d_in[3];
  float* Out = (float*)d_out;

  u16* Kb = (u16*)d_ws;
  u16* Vb = Kb + (size_t)NB * SL2 * HD;  // needs 2 * 16 MiB of ws

  cvt_bf16_kernel<<<2048, 256, 0, stream>>>(K, V, Kb, Vb);
  attn_fwd<<<NB * (SL1 / QBLK), 512, 0, stream>>>(Q, Kb, Vb, lenp, Out);
}